// Round 1
// baseline (743.998 us; speedup 1.0000x reference)
//
#include <hip/hip_runtime.h>
#include <stdint.h>

// ---------- helpers ----------
typedef __attribute__((ext_vector_type(8))) short short8;   // 8 x bf16 (4 VGPRs)
typedef __attribute__((ext_vector_type(4))) float floatx4;  // MFMA accum

__device__ __forceinline__ unsigned short f2bf(float f) {
  union { float f; unsigned int u; } c; c.f = f;
  unsigned int u = c.u;
  unsigned int r = (u + 0x7fffu + ((u >> 16) & 1u)) >> 16;  // RNE
  return (unsigned short)r;
}
__device__ __forceinline__ float bf2f(unsigned short h) {
  union { unsigned int u; float f; } c; c.u = ((unsigned int)h) << 16;
  return c.f;
}

// async global->LDS, 16B per lane. LDS dest is wave-uniform base + lane*16,
// so the flat LDS layout must match lane order exactly (no padding).
__device__ __forceinline__ void load16_to_lds(const void* g, void* l) {
  __builtin_amdgcn_global_load_lds(
      (const __attribute__((address_space(1))) unsigned int*)g,
      (__attribute__((address_space(3))) unsigned int*)l, 16, 0, 0);
}

// ---------- elementwise kernels ----------
__global__ void f32_to_bf16_kernel(const float* __restrict__ in,
                                   unsigned short* __restrict__ out, long n4) {
  long i = blockIdx.x * (long)blockDim.x + threadIdx.x;
  if (i >= n4) return;
  float4 v = ((const float4*)in)[i];
  ushort4 o;
  o.x = f2bf(v.x); o.y = f2bf(v.y); o.z = f2bf(v.z); o.w = f2bf(v.w);
  ((ushort4*)out)[i] = o;
}

// w[n,k] (fp8 values stored as fp32) * s[n/128, k/128] -> bf16
__global__ void dequant_kernel(const float* __restrict__ wq,
                               const float* __restrict__ s,
                               unsigned short* __restrict__ out,
                               int K, int sK, long n4) {
  long i = blockIdx.x * (long)blockDim.x + threadIdx.x;
  if (i >= n4) return;
  long e = i * 4;
  int n = (int)(e / K);
  int k = (int)(e - (long)n * K);
  float sc = s[(n >> 7) * sK + (k >> 7)];
  float4 v = ((const float4*)wq)[i];
  ushort4 o;
  o.x = f2bf(v.x * sc); o.y = f2bf(v.y * sc);
  o.z = f2bf(v.z * sc); o.w = f2bf(v.w * sc);
  ((ushort4*)out)[i] = o;
}

__global__ void silu_mul_kernel(const unsigned short* __restrict__ g,
                                const unsigned short* __restrict__ u,
                                unsigned short* __restrict__ out, long n4) {
  long i = blockIdx.x * (long)blockDim.x + threadIdx.x;
  if (i >= n4) return;
  ushort4 gv = ((const ushort4*)g)[i];
  ushort4 uv = ((const ushort4*)u)[i];
  float g0 = bf2f(gv.x), g1 = bf2f(gv.y), g2 = bf2f(gv.z), g3 = bf2f(gv.w);
  ushort4 o;
  o.x = f2bf(g0 / (1.f + __expf(-g0)) * bf2f(uv.x));
  o.y = f2bf(g1 / (1.f + __expf(-g1)) * bf2f(uv.y));
  o.z = f2bf(g2 / (1.f + __expf(-g2)) * bf2f(uv.z));
  o.w = f2bf(g3 / (1.f + __expf(-g3)) * bf2f(uv.w));
  ((ushort4*)out)[i] = o;
}

// ---------- GEMM: C[M,N] = A[M,K] * B[N,K]^T, bf16 in, fp32 accum ----------
// 128x128 tile / block, 256 threads = 4 waves (2x2), each wave 64x64 via
// 4x4 grid of mfma_f32_16x16x32_bf16. m97-style 2-barrier K-loop with
// global_load_lds width-16 staging.
template <int OUT_BF16>
__global__ __launch_bounds__(256) void gemm_nt(
    const unsigned short* __restrict__ A,  // [M,K] bf16
    const unsigned short* __restrict__ B,  // [N,K] bf16
    void* __restrict__ C,                  // [M,N] fp32 or bf16
    int M, int N, int K) {
  __shared__ unsigned short As[128 * 32];
  __shared__ unsigned short Bs[128 * 32];

  const int tid = threadIdx.x;
  const int lane = tid & 63;
  const int wave = tid >> 6;
  const int wm = wave >> 1, wn = wave & 1;
  const int m0 = blockIdx.y * 128, n0 = blockIdx.x * 128;

  // staging: flat [128][32] row-major; thread t covers 8 bf16 at flat t*8
  const int f0 = tid * 8;
  const int ar = f0 >> 5;   // row 0..63 (chunk 0), +64 for chunk 1
  const int ac = f0 & 31;

  const int q = lane >> 4;    // quad 0..3 -> k offset q*8
  const int r16 = lane & 15;  // row/col within 16

  floatx4 acc[4][4];
#pragma unroll
  for (int i = 0; i < 4; i++)
#pragma unroll
    for (int j = 0; j < 4; j++) acc[i][j] = (floatx4){0.f, 0.f, 0.f, 0.f};

  const unsigned short* Abase = A + (size_t)m0 * K;
  const unsigned short* Bbase = B + (size_t)n0 * K;

  for (int k0 = 0; k0 < K; k0 += 32) {
    load16_to_lds(Abase + (size_t)ar * K + k0 + ac, &As[f0]);
    load16_to_lds(Abase + (size_t)(64 + ar) * K + k0 + ac, &As[2048 + f0]);
    load16_to_lds(Bbase + (size_t)ar * K + k0 + ac, &Bs[f0]);
    load16_to_lds(Bbase + (size_t)(64 + ar) * K + k0 + ac, &Bs[2048 + f0]);
    __syncthreads();  // drains vmcnt(0) then barrier (compiler-inserted)

    short8 a[4], b[4];
#pragma unroll
    for (int t = 0; t < 4; t++) {
      a[t] = *(const short8*)&As[(wm * 64 + t * 16 + r16) * 32 + q * 8];
      b[t] = *(const short8*)&Bs[(wn * 64 + t * 16 + r16) * 32 + q * 8];
    }
#pragma unroll
    for (int i = 0; i < 4; i++)
#pragma unroll
      for (int j = 0; j < 4; j++)
        acc[i][j] =
            __builtin_amdgcn_mfma_f32_16x16x32_bf16(a[i], b[j], acc[i][j], 0, 0, 0);
    __syncthreads();  // protect LDS before next stage
  }

  // epilogue: D col = lane&15, row = quad*4 + reg (m89/m91-verified)
#pragma unroll
  for (int i = 0; i < 4; i++) {
    int row0 = m0 + wm * 64 + i * 16 + q * 4;
#pragma unroll
    for (int j = 0; j < 4; j++) {
      int col = n0 + wn * 64 + j * 16 + r16;
#pragma unroll
      for (int rr = 0; rr < 4; rr++) {
        size_t off = (size_t)(row0 + rr) * N + col;
        if (OUT_BF16)
          ((unsigned short*)C)[off] = f2bf(acc[i][j][rr]);
        else
          ((float*)C)[off] = acc[i][j][rr];
      }
    }
  }
}

// ---------- launch ----------
extern "C" void kernel_launch(void* const* d_in, const int* in_sizes, int n_in,
                              void* d_out, int out_size, void* d_ws, size_t ws_size,
                              hipStream_t stream) {
  const float* x = (const float*)d_in[0];
  const float* w1q = (const float*)d_in[1];
  const float* w1s = (const float*)d_in[2];
  const float* w3q = (const float*)d_in[3];
  const float* w3s = (const float*)d_in[4];
  const float* w2q = (const float*)d_in[5];
  const float* w2s = (const float*)d_in[6];

  const int T = 4096, H = 2048, F = 7168;

  char* ws = (char*)d_ws;
  unsigned short* xb = (unsigned short*)ws;  ws += (size_t)T * H * 2;   // 16.8 MB
  unsigned short* wb = (unsigned short*)ws;  ws += (size_t)F * H * 2;   // 29.4 MB (reused w1/w3/w2)
  unsigned short* g  = (unsigned short*)ws;  ws += (size_t)T * F * 2;   // 58.7 MB
  unsigned short* u  = (unsigned short*)ws;  ws += (size_t)T * F * 2;   // 58.7 MB
  // total ~163.6 MB of d_ws

  long xn4 = (long)T * H / 4;
  long wn4 = (long)F * H / 4;
  long sn4 = (long)T * F / 4;

  f32_to_bf16_kernel<<<(xn4 + 255) / 256, 256, 0, stream>>>(x, xb, xn4);

  // g = x @ w1^T
  dequant_kernel<<<(wn4 + 255) / 256, 256, 0, stream>>>(w1q, w1s, wb, H, H / 128, wn4);
  gemm_nt<1><<<dim3(F / 128, T / 128), 256, 0, stream>>>(xb, wb, g, T, F, H);

  // u = x @ w3^T
  dequant_kernel<<<(wn4 + 255) / 256, 256, 0, stream>>>(w3q, w3s, wb, H, H / 128, wn4);
  gemm_nt<1><<<dim3(F / 128, T / 128), 256, 0, stream>>>(xb, wb, u, T, F, H);

  // fused = silu(g) * u   (in place over g)
  silu_mul_kernel<<<(sn4 + 255) / 256, 256, 0, stream>>>(g, u, g, sn4);

  // out = fused @ w2^T  (fp32 out)
  dequant_kernel<<<(wn4 + 255) / 256, 256, 0, stream>>>(w2q, w2s, wb, F, F / 128, wn4);
  gemm_nt<0><<<dim3(H / 128, T / 128), 256, 0, stream>>>(g, wb, d_out, T, H, F);
}